// Round 6
// baseline (680.865 us; speedup 1.0000x reference)
//
#include <hip/hip_runtime.h>
#include <hip/hip_bf16.h>
#include <math.h>

// ---------------------------------------------------------------------------
// DiT block: B=4 L=2048 D=1024 H=16 HD=64 MLP=4096.
// I/O fp32; internal bf16 MFMA, fp32 accumulate.
// Workspace (bytes):
//   [0        ) WqkvT [3072][1024]   (dead after qkv GEMM; reused as W2 p0)
//   [6291456  ) WprojT[1024][1024]
//   [8388608  ) W1T   [4096][1024]
//   [16777216 ) W2T   [1024][4096]   (live through W2)
//   [25165824 ) WtT   [6144][1024]
//   [37748736 ) tp    [4][6144] f32
//   [37847040 ) hbuf  [8192][1024] bf16  (LN1 out -> vT[64][64][2048] -> LN2 out -> W2 p1)
//   [54624256 ) qkv   [8192][3072] bf16  } overlaid midb [8192][4096]
//   [121733120) attnb [8192][1024] bf16
//   [138510336) x1    [8192][1024] f32   (ends 172064768)
// ---------------------------------------------------------------------------

typedef __attribute__((ext_vector_type(8))) __bf16 bf16x8;
typedef __attribute__((ext_vector_type(4))) float f32x4;

union FragU { uint4 u; bf16x8 b; };

#define AS1(p) ((const __attribute__((address_space(1))) void*)(p))
#define AS3(p) ((__attribute__((address_space(3))) void*)(p))

__device__ __forceinline__ float bflo(uint u) {
    union { uint i; float f; } v; v.i = u << 16; return v.f;
}
__device__ __forceinline__ float bfhi(uint u) {
    union { uint i; float f; } v; v.i = u & 0xffff0000u; return v.f;
}
__device__ __forceinline__ ushort f2bf(float f) {
    union { float f; uint i; } v; v.f = f;
    uint r = (v.i + 0x7fffu + ((v.i >> 16) & 1u)) >> 16;
    return (ushort)r;
}
// truncating bf16 pair pack: low half <- a, high half <- b (1 v_perm_b32)
__device__ __forceinline__ uint pkbf(float a, float b) {
    return __builtin_amdgcn_perm(__float_as_uint(b), __float_as_uint(a), 0x07060302u);
}
__device__ __forceinline__ void stval(ushort* p, float v) { *p = f2bf(v); }
__device__ __forceinline__ void stval(float* p, float v) { *p = v; }

// ---------------------------------------------------------------------------
// Transpose + fp32->bf16: in [R][C] f32 -> out [C][R] bf16.
// ---------------------------------------------------------------------------
__global__ __launch_bounds__(256) void transpose_f2b(const float* __restrict__ in,
                                                     ushort* __restrict__ out,
                                                     int R, int C) {
    __shared__ ushort t[32][33];
    int c0 = blockIdx.x * 32, r0 = blockIdx.y * 32;
    int tx = threadIdx.x, ty = threadIdx.y;  // block (32, 8)
#pragma unroll
    for (int i = 0; i < 32; i += 8)
        t[ty + i][tx] = f2bf(in[(size_t)(r0 + ty + i) * C + c0 + tx]);
    __syncthreads();
#pragma unroll
    for (int i = 0; i < 32; i += 8)
        out[(size_t)(c0 + ty + i) * R + r0 + tx] = t[tx][ty + i];
}

// ---------------------------------------------------------------------------
// V transpose: qkv [8192][3072] (V = cols 2048+h*64+d) -> vT[bh=64][d=64][l=2048]
// Grid 2048 = 64 bh x 32 l-tiles. Reads coalesced (d fast dim); writes 16B/lane.
// ---------------------------------------------------------------------------
__global__ __launch_bounds__(256) void transpose_v(const ushort* __restrict__ qkv,
                                                   ushort* __restrict__ vT) {
    int bh = blockIdx.x >> 5, lt = blockIdx.x & 31;
    int b = bh >> 4, h = bh & 15;
    int d = threadIdx.x & 63, lg = threadIdx.x >> 6;
    const ushort* src = qkv + (size_t)b * 2048 * 3072 + 2048 + h * 64 + d;
#pragma unroll
    for (int g = 0; g < 2; g++) {
        int l0 = lt * 64 + lg * 16 + g * 8;
        ushort v[8];
#pragma unroll
        for (int i = 0; i < 8; i++) v[i] = src[(size_t)(l0 + i) * 3072];
        *(uint4*)&vT[((size_t)bh * 64 + d) * 2048 + l0] = *(uint4*)v;
    }
}

// ---------------------------------------------------------------------------
// tp = silu(time_emb) @ Wt + bt.  One wave per output element (b, n).
// ---------------------------------------------------------------------------
__global__ __launch_bounds__(256) void tp_gemm(const float* __restrict__ te,
                                               const ushort* __restrict__ WtT,
                                               const float* __restrict__ bt,
                                               float* __restrict__ tp) {
    int w = blockIdx.x * 4 + (threadIdx.x >> 6);
    int lane = threadIdx.x & 63;
    int b = w / 6144, n = w % 6144;
    const ushort* wr = WtT + (size_t)n * 1024;
    const float* tr = te + (size_t)b * 1024;
    float s = 0.f;
#pragma unroll
    for (int i = 0; i < 16; i++) {
        int k = lane + 64 * i;
        float t = tr[k];
        float sil = t / (1.f + __expf(-t));
        s += sil * bflo((uint)wr[k]);
    }
#pragma unroll
    for (int x = 32; x; x >>= 1) s += __shfl_xor(s, x);
    if (lane == 0) tp[(size_t)b * 6144 + n] = s + bt[n];
}

// ---------------------------------------------------------------------------
// Fused LayerNorm + AdaLN modulate: out = (ln(x)*g+be)*(1+scale)+shift.
// ---------------------------------------------------------------------------
__global__ __launch_bounds__(256) void ln_mod(const float* __restrict__ x,
                                              const float* __restrict__ tpb,
                                              const float* __restrict__ g,
                                              const float* __restrict__ be,
                                              ushort* __restrict__ out,
                                              int shift_off, int scale_off) {
    __shared__ float2 sred[4];
    int row = blockIdx.x;
    int b = row >> 11;
    int tid = threadIdx.x;
    float4 f = *(const float4*)&x[(size_t)row * 1024 + tid * 4];
    float v[4] = {f.x, f.y, f.z, f.w};
    float s = v[0] + v[1] + v[2] + v[3];
    float s2 = v[0] * v[0] + v[1] * v[1] + v[2] * v[2] + v[3] * v[3];
#pragma unroll
    for (int m = 32; m; m >>= 1) { s += __shfl_xor(s, m); s2 += __shfl_xor(s2, m); }
    if ((tid & 63) == 0) sred[tid >> 6] = make_float2(s, s2);
    __syncthreads();
    s = sred[0].x + sred[1].x + sred[2].x + sred[3].x;
    s2 = sred[0].y + sred[1].y + sred[2].y + sred[3].y;
    float mu = s * (1.f / 1024.f);
    float var = s2 * (1.f / 1024.f) - mu * mu;
    float rs = rsqrtf(var + 1e-5f);
    const float* tprow = tpb + (size_t)b * 6144;
    ushort o4[4];
#pragma unroll
    for (int t = 0; t < 4; t++) {
        int c = tid * 4 + t;
        float y = (v[t] - mu) * rs * g[c] + be[c];
        y = y * (1.f + tprow[scale_off + c]) + tprow[shift_off + c];
        o4[t] = f2bf(y);
    }
    *(uint2*)&out[(size_t)row * 1024 + tid * 4] = *(uint2*)o4;
}

// ---------------------------------------------------------------------------
// MFMA bf16 GEMM with global_load_lds staging. 128x128 tile, BK=32.
// EPI 0: +bias   EPI 1: gelu(+bias)   EPI 2: res + gate*( +bias )
// ---------------------------------------------------------------------------
template <int EPI, typename OT>
__global__ __launch_bounds__(256) void gemm_bt(const ushort* __restrict__ A,
                                               const ushort* __restrict__ BT,
                                               const float* __restrict__ bias,
                                               OT* __restrict__ C,
                                               int M, int N, int K,
                                               const float* __restrict__ res,
                                               const float* __restrict__ tpb,
                                               int goff) {
    __shared__ __align__(16) ushort As[128 * 32];
    __shared__ __align__(16) ushort Bs[128 * 32];
    int m0 = blockIdx.y * 128, n0 = blockIdx.x * 128;
    int tid = threadIdx.x;
    int wid = tid >> 6, lane = tid & 63;
    int wy = wid >> 1, wx = wid & 1;
    int r16 = lane & 15;
    int q8 = (lane >> 4) << 3;

    f32x4 acc[4][4];
#pragma unroll
    for (int i = 0; i < 4; i++)
#pragma unroll
        for (int j = 0; j < 4; j++) acc[i][j] = (f32x4){0.f, 0.f, 0.f, 0.f};

    int sr = tid >> 2;            // 0..63
    int sc = (tid & 3) << 3;      // 0,8,16,24
    const ushort* Abase = A + (size_t)(m0 + sr) * K + sc;
    const ushort* Bbase = BT + (size_t)(n0 + sr) * K + sc;
    ushort* AsW = As + (size_t)wid * 512;
    ushort* BsW = Bs + (size_t)wid * 512;

    for (int k0 = 0; k0 < K; k0 += 32) {
        __builtin_amdgcn_global_load_lds(AS1(Abase + k0), AS3(AsW), 16, 0, 0);
        __builtin_amdgcn_global_load_lds(AS1(Abase + (size_t)64 * K + k0), AS3(AsW + 2048), 16, 0, 0);
        __builtin_amdgcn_global_load_lds(AS1(Bbase + k0), AS3(BsW), 16, 0, 0);
        __builtin_amdgcn_global_load_lds(AS1(Bbase + (size_t)64 * K + k0), AS3(BsW + 2048), 16, 0, 0);
        __syncthreads();
        FragU fa[4], fb[4];
#pragma unroll
        for (int i = 0; i < 4; i++)
            fa[i].u = *(const uint4*)&As[(wy * 64 + i * 16 + r16) * 32 + q8];
#pragma unroll
        for (int j = 0; j < 4; j++)
            fb[j].u = *(const uint4*)&Bs[(wx * 64 + j * 16 + r16) * 32 + q8];
#pragma unroll
        for (int i = 0; i < 4; i++)
#pragma unroll
            for (int j = 0; j < 4; j++)
                acc[i][j] = __builtin_amdgcn_mfma_f32_16x16x32_bf16(fa[i].b, fb[j].b, acc[i][j], 0, 0, 0);
        __syncthreads();
    }

    int q4 = (lane >> 4) << 2;
#pragma unroll
    for (int i = 0; i < 4; i++) {
#pragma unroll
        for (int j = 0; j < 4; j++) {
            int col = n0 + wx * 64 + j * 16 + r16;
            float bv = bias[col];
#pragma unroll
            for (int t = 0; t < 4; t++) {
                int row = m0 + wy * 64 + i * 16 + q4 + t;
                float v = acc[i][j][t] + bv;
                if constexpr (EPI == 1) {
                    v = 0.5f * v * (1.f + erff(v * 0.70710678118f));
                }
                if constexpr (EPI == 2) {
                    float rv = res[(size_t)row * N + col];
                    float gate = tpb[(size_t)(row >> 11) * 6144 + goff + col];
                    v = rv + gate * v;
                }
                stval(&C[(size_t)row * N + col], v);
            }
        }
    }
}

// ---------------------------------------------------------------------------
// Split-K GEMM for W2: z = blockIdx.z selects K-half (2048). Writes bf16
// partials (no bias) to p0/p1. A [8192][4096], BT [1024][4096].
// ---------------------------------------------------------------------------
__global__ __launch_bounds__(256) void gemm_sk(const ushort* __restrict__ A,
                                               const ushort* __restrict__ BT,
                                               ushort* __restrict__ p0,
                                               ushort* __restrict__ p1) {
    __shared__ __align__(16) ushort As[128 * 32];
    __shared__ __align__(16) ushort Bs[128 * 32];
    int m0 = blockIdx.y * 128, n0 = blockIdx.x * 128;
    int z = blockIdx.z;
    int tid = threadIdx.x;
    int wid = tid >> 6, lane = tid & 63;
    int wy = wid >> 1, wx = wid & 1;
    int r16 = lane & 15;
    int q8 = (lane >> 4) << 3;

    f32x4 acc[4][4];
#pragma unroll
    for (int i = 0; i < 4; i++)
#pragma unroll
        for (int j = 0; j < 4; j++) acc[i][j] = (f32x4){0.f, 0.f, 0.f, 0.f};

    int sr = tid >> 2;
    int sc = (tid & 3) << 3;
    const ushort* Abase = A + (size_t)(m0 + sr) * 4096 + z * 2048 + sc;
    const ushort* Bbase = BT + (size_t)(n0 + sr) * 4096 + z * 2048 + sc;
    ushort* AsW = As + (size_t)wid * 512;
    ushort* BsW = Bs + (size_t)wid * 512;

    for (int k0 = 0; k0 < 2048; k0 += 32) {
        __builtin_amdgcn_global_load_lds(AS1(Abase + k0), AS3(AsW), 16, 0, 0);
        __builtin_amdgcn_global_load_lds(AS1(Abase + (size_t)64 * 4096 + k0), AS3(AsW + 2048), 16, 0, 0);
        __builtin_amdgcn_global_load_lds(AS1(Bbase + k0), AS3(BsW), 16, 0, 0);
        __builtin_amdgcn_global_load_lds(AS1(Bbase + (size_t)64 * 4096 + k0), AS3(BsW + 2048), 16, 0, 0);
        __syncthreads();
        FragU fa[4], fb[4];
#pragma unroll
        for (int i = 0; i < 4; i++)
            fa[i].u = *(const uint4*)&As[(wy * 64 + i * 16 + r16) * 32 + q8];
#pragma unroll
        for (int j = 0; j < 4; j++)
            fb[j].u = *(const uint4*)&Bs[(wx * 64 + j * 16 + r16) * 32 + q8];
#pragma unroll
        for (int i = 0; i < 4; i++)
#pragma unroll
            for (int j = 0; j < 4; j++)
                acc[i][j] = __builtin_amdgcn_mfma_f32_16x16x32_bf16(fa[i].b, fb[j].b, acc[i][j], 0, 0, 0);
        __syncthreads();
    }

    ushort* P = z ? p1 : p0;
    int q4 = (lane >> 4) << 2;
#pragma unroll
    for (int i = 0; i < 4; i++)
#pragma unroll
        for (int j = 0; j < 4; j++) {
            int col = n0 + wx * 64 + j * 16 + r16;
#pragma unroll
            for (int t = 0; t < 4; t++) {
                int row = m0 + wy * 64 + i * 16 + q4 + t;
                P[(size_t)row * 1024 + col] = f2bf(acc[i][j][t]);
            }
        }
}

// ---------------------------------------------------------------------------
// W2 reduce: out = x1 + gate_mlp * (p0 + p1 + b2).
// ---------------------------------------------------------------------------
__global__ __launch_bounds__(256) void w2_reduce(const ushort* __restrict__ p0,
                                                 const ushort* __restrict__ p1,
                                                 const float* __restrict__ x1,
                                                 const float* __restrict__ b2,
                                                 const float* __restrict__ tpb,
                                                 float* __restrict__ out) {
    int row = blockIdx.x;
    int b = row >> 11;
    int c = threadIdx.x * 4;
    size_t off = (size_t)row * 1024 + c;
    uint2 u0 = *(const uint2*)&p0[off];
    uint2 u1 = *(const uint2*)&p1[off];
    float4 xr = *(const float4*)&x1[off];
    const float* gp = tpb + (size_t)b * 6144 + 5120 + c;
    float4 o;
    o.x = xr.x + gp[0] * (bflo(u0.x) + bflo(u1.x) + b2[c + 0]);
    o.y = xr.y + gp[1] * (bfhi(u0.x) + bfhi(u1.x) + b2[c + 1]);
    o.z = xr.z + gp[2] * (bflo(u0.y) + bflo(u1.y) + b2[c + 2]);
    o.w = xr.w + gp[3] * (bfhi(u0.y) + bfhi(u1.y) + b2[c + 3]);
    *(float4*)&out[off] = o;
}

// ---------------------------------------------------------------------------
// MFMA flash attention, transposed-S formulation (see R5). V comes from the
// pre-transposed vT[bh][d][l] buffer -> plain uint4 staging, no swizzle.
// LDS: Ks[64][72] + Vs[64][72] + Ps[64][72] = 27 KB.
// ---------------------------------------------------------------------------
__global__ __launch_bounds__(256, 4) void attn_mfma(const ushort* __restrict__ qkv,
                                                    const ushort* __restrict__ vT,
                                                    ushort* __restrict__ out) {
    __shared__ __align__(16) ushort Ks[64 * 72];
    __shared__ __align__(16) ushort Vs[64 * 72];
    __shared__ __align__(16) ushort Ps[64 * 72];   // Q staging in phase 0

    int tid = threadIdx.x;
    int wid = tid >> 6, lane = tid & 63;
    int r16 = lane & 15, quad = lane >> 4;
    int q8 = quad << 3, q4 = quad << 2;

    int bh = blockIdx.x >> 5;        // 0..63
    int qt = blockIdx.x & 31;        // 0..31
    int b = bh >> 4, h = bh & 15;
    const ushort* qkbase = qkv + (size_t)b * 2048 * 3072 + h * 64;

    // ---- phase 0: stage Q tile [64][64] into Ps, load wave's Q frags ----
    {
        int r = tid >> 2;                 // 0..63
        int c = (tid & 3) << 4;           // 0,16,32,48
        const ushort* qp = qkbase + (size_t)(qt * 64 + r) * 3072 + c;
        *(uint4*)&Ps[r * 72 + c] = *(const uint4*)qp;
        *(uint4*)&Ps[r * 72 + c + 8] = *(const uint4*)(qp + 8);
    }
    __syncthreads();
    FragU qa[2];
#pragma unroll
    for (int ks = 0; ks < 2; ks++)
        qa[ks].u = *(const uint4*)&Ps[(wid * 16 + r16) * 72 + ks * 32 + q8];
    // From here each wave only touches its own 16 Ps rows (wave-private).

    float m_ = -1e30f, l_ = 0.f;          // scalars: this lane's q-row = r16
    f32x4 o[4];
#pragma unroll
    for (int dn = 0; dn < 4; dn++) o[dn] = (f32x4){0.f, 0.f, 0.f, 0.f};

    int kr = tid >> 2;                    // 0..63
    int kc = (tid & 3) << 4;              // 0,16,32,48
    const ushort* kptr = qkbase + 1024 + (size_t)kr * 3072 + kc;
    const ushort* vptr = vT + (size_t)bh * 131072 + (size_t)kr * 2048 + kc;

    // prefetch tile 0
    uint4 ka0 = *(const uint4*)kptr;
    uint4 ka1 = *(const uint4*)(kptr + 8);
    uint4 va0 = *(const uint4*)vptr;
    uint4 va1 = *(const uint4*)(vptr + 8);

    for (int kt = 0; kt < 32; kt++) {
        __syncthreads();   // previous tile's LDS readers done
        *(uint4*)&Ks[kr * 72 + kc] = ka0;
        *(uint4*)&Ks[kr * 72 + kc + 8] = ka1;
        *(uint4*)&Vs[kr * 72 + kc] = va0;
        *(uint4*)&Vs[kr * 72 + kc + 8] = va1;
        __syncthreads();

        // prefetch next tile; loads complete during compute below
        if (kt < 31) {
            const ushort* kp2 = kptr + (size_t)(kt + 1) * 64 * 3072;
            const ushort* vp2 = vptr + (kt + 1) * 64;
            ka0 = *(const uint4*)kp2;
            ka1 = *(const uint4*)(kp2 + 8);
            va0 = *(const uint4*)vp2;
            va1 = *(const uint4*)(vp2 + 8);
        }

        // ---- S^T = K Q^T  (lane holds keys n*16+q4+t for q-row r16) ----
        f32x4 s[4];
#pragma unroll
        for (int n = 0; n < 4; n++) s[n] = (f32x4){0.f, 0.f, 0.f, 0.f};
#pragma unroll
        for (int ks = 0; ks < 2; ks++) {
            FragU kb[4];
#pragma unroll
            for (int n = 0; n < 4; n++)
                kb[n].u = *(const uint4*)&Ks[(n * 16 + r16) * 72 + ks * 32 + q8];
#pragma unroll
            for (int n = 0; n < 4; n++)
                s[n] = __builtin_amdgcn_mfma_f32_16x16x32_bf16(kb[n].b, qa[ks].b, s[n], 0, 0, 0);
        }

        // ---- online softmax: scalar per lane, keys in-lane + across quads ----
        float mx = fmaxf(fmaxf(fmaxf(s[0][0], s[0][1]), fmaxf(s[0][2], s[0][3])),
                         fmaxf(fmaxf(s[1][0], s[1][1]), fmaxf(s[1][2], s[1][3])));
        mx = fmaxf(mx, fmaxf(fmaxf(fmaxf(s[2][0], s[2][1]), fmaxf(s[2][2], s[2][3])),
                             fmaxf(fmaxf(s[3][0], s[3][1]), fmaxf(s[3][2], s[3][3]))));
        mx = fmaxf(mx, __shfl_xor(mx, 16));
        mx = fmaxf(mx, __shfl_xor(mx, 32));
        float nm = fmaxf(m_, mx);
        float al = __expf((m_ - nm) * 0.125f);
        float cc = nm * 0.125f;
        m_ = nm;

        float p[4][4];
        float ps = 0.f;
#pragma unroll
        for (int n = 0; n < 4; n++)
#pragma unroll
            for (int t = 0; t < 4; t++) {
                p[n][t] = __expf(__fmaf_rn(s[n][t], 0.125f, -cc));
                ps += p[n][t];
            }
        ps += __shfl_xor(ps, 16);
        ps += __shfl_xor(ps, 32);
        l_ = l_ * al + ps;
#pragma unroll
        for (int dn = 0; dn < 4; dn++)
#pragma unroll
            for (int t = 0; t < 4; t++) o[dn][t] *= al;

        // ---- P -> Ps[qrow=r16][key] (wave-private rows, 4x b64 writes) ----
#pragma unroll
        for (int n = 0; n < 4; n++) {
            uint2 w2 = make_uint2(pkbf(p[n][0], p[n][1]), pkbf(p[n][2], p[n][3]));
            *(uint2*)&Ps[(wid * 16 + r16) * 72 + n * 16 + q4] = w2;
        }

        // ---- O^T += V^T P^T ----
#pragma unroll
        for (int ks = 0; ks < 2; ks++) {
            FragU pa, vb[4];
            pa.u = *(const uint4*)&Ps[(wid * 16 + r16) * 72 + ks * 32 + q8];
#pragma unroll
            for (int dn = 0; dn < 4; dn++)
                vb[dn].u = *(const uint4*)&Vs[(dn * 16 + r16) * 72 + ks * 32 + q8];
#pragma unroll
            for (int dn = 0; dn < 4; dn++)
                o[dn] = __builtin_amdgcn_mfma_f32_16x16x32_bf16(vb[dn].b, pa.b, o[dn], 0, 0, 0);
        }
    }

    // ---- epilogue: lane holds O^T[d=dn*16+q4+t][qrow=r16] ----
    float inv = 1.f / l_;
    int row = qt * 64 + wid * 16 + r16;
    ushort* orow = out + (size_t)(b * 2048 + row) * 1024 + h * 64;
#pragma unroll
    for (int dn = 0; dn < 4; dn++) {
        uint2 w2 = make_uint2(pkbf(o[dn][0] * inv, o[dn][1] * inv),
                              pkbf(o[dn][2] * inv, o[dn][3] * inv));
        *(uint2*)&orow[dn * 16 + q4] = w2;
    }
}

// ---------------------------------------------------------------------------
extern "C" void kernel_launch(void* const* d_in, const int* in_sizes, int n_in,
                              void* d_out, int out_size, void* d_ws, size_t ws_size,
                              hipStream_t stream) {
    const float* x    = (const float*)d_in[0];
    const float* te   = (const float*)d_in[1];
    const float* Wqkv = (const float*)d_in[2];
    const float* bqkv = (const float*)d_in[3];
    const float* Wproj= (const float*)d_in[4];
    const float* bproj= (const float*)d_in[5];
    const float* W1   = (const float*)d_in[6];
    const float* b1   = (const float*)d_in[7];
    const float* W2   = (const float*)d_in[8];
    const float* b2   = (const float*)d_in[9];
    const float* Wt   = (const float*)d_in[10];
    const float* bt   = (const float*)d_in[11];
    const float* g1   = (const float*)d_in[12];
    const float* be1  = (const float*)d_in[13];
    const float* g2   = (const float*)d_in[14];
    const float* be2  = (const float*)d_in[15];

    char* ws = (char*)d_ws;
    ushort* WqkvT  = (ushort*)(ws + 0);
    ushort* WprojT = (ushort*)(ws + 6291456);
    ushort* W1T    = (ushort*)(ws + 8388608);
    ushort* W2T    = (ushort*)(ws + 16777216);
    ushort* WtT    = (ushort*)(ws + 25165824);
    float*  tpb    = (float*)(ws + 37748736);
    ushort* hbuf   = (ushort*)(ws + 37847040);
    ushort* vTb    = (ushort*)(ws + 37847040);   // overlays hbuf (dead there)
    ushort* qkvb   = (ushort*)(ws + 54624256);
    ushort* midb   = (ushort*)(ws + 54624256);   // overlays qkv (dead by then)
    ushort* attnb  = (ushort*)(ws + 121733120);
    float*  x1b    = (float*)(ws + 138510336);
    ushort* p0b    = (ushort*)(ws + 0);          // overlays WqkvT..W1T (dead)
    ushort* p1b    = (ushort*)(ws + 37847040);   // overlays hbuf (dead)

    dim3 tb(32, 8);
    hipLaunchKernelGGL(transpose_f2b, dim3(3072 / 32, 1024 / 32), tb, 0, stream, Wqkv, WqkvT, 1024, 3072);
    hipLaunchKernelGGL(transpose_f2b, dim3(1024 / 32, 1024 / 32), tb, 0, stream, Wproj, WprojT, 1024, 1024);
    hipLaunchKernelGGL(transpose_f2b, dim3(4096 / 32, 1024 / 32), tb, 0, stream, W1, W1T, 1024, 4096);
    hipLaunchKernelGGL(transpose_f2b, dim3(1024 / 32, 4096 / 32), tb, 0, stream, W2, W2T, 4096, 1024);
    hipLaunchKernelGGL(transpose_f2b, dim3(6144 / 32, 1024 / 32), tb, 0, stream, Wt, WtT, 1024, 6144);

    hipLaunchKernelGGL(tp_gemm, dim3(6144), dim3(256), 0, stream, te, WtT, bt, tpb);

    // LN1 + modulate (shift_msa @0, scale_msa @1024)
    hipLaunchKernelGGL(ln_mod, dim3(8192), dim3(256), 0, stream, x, tpb, g1, be1, hbuf, 0, 1024);

    // qkv = h @ Wqkv + bqkv
    hipLaunchKernelGGL((gemm_bt<0, ushort>), dim3(3072 / 128, 8192 / 128), dim3(256), 0, stream,
                       hbuf, WqkvT, bqkv, qkvb, 8192, 3072, 1024, (const float*)nullptr, (const float*)nullptr, 0);

    // V -> vT[bh][d][l]  (hbuf region is dead after the qkv GEMM consumed it)
    hipLaunchKernelGGL(transpose_v, dim3(2048), dim3(256), 0, stream, qkvb, vTb);

    hipLaunchKernelGGL(attn_mfma, dim3(2048), dim3(256), 0, stream, qkvb, vTb, attnb);

    // x1 = x + gate_msa * (attn @ Wproj + bproj)   (gate_msa @2048)
    hipLaunchKernelGGL((gemm_bt<2, float>), dim3(1024 / 128, 8192 / 128), dim3(256), 0, stream,
                       attnb, WprojT, bproj, x1b, 8192, 1024, 1024, x, tpb, 2048);

    // LN2 + modulate (shift_mlp @3072, scale_mlp @4096)
    hipLaunchKernelGGL(ln_mod, dim3(8192), dim3(256), 0, stream, x1b, tpb, g2, be2, hbuf, 3072, 4096);

    // mid = gelu(h @ W1 + b1)
    hipLaunchKernelGGL((gemm_bt<1, ushort>), dim3(4096 / 128, 8192 / 128), dim3(256), 0, stream,
                       hbuf, W1T, b1, midb, 8192, 4096, 1024, (const float*)nullptr, (const float*)nullptr, 0);

    // W2 split-K: partials p0/p1 (bf16), then reduce with gate_mlp (@5120)
    hipLaunchKernelGGL(gemm_sk, dim3(8, 64, 2), dim3(256), 0, stream, midb, W2T, p0b, p1b);
    hipLaunchKernelGGL(w2_reduce, dim3(8192), dim3(256), 0, stream, p0b, p1b, x1b, b2, tpb, (float*)d_out);
}

// Round 7
// 666.797 us; speedup vs baseline: 1.0211x; 1.0211x over previous
//
#include <hip/hip_runtime.h>
#include <hip/hip_bf16.h>
#include <math.h>

// ---------------------------------------------------------------------------
// DiT block: B=4 L=2048 D=1024 H=16 HD=64 MLP=4096.
// I/O fp32; internal bf16 MFMA, fp32 accumulate.
// Workspace (bytes):
//   [0        ) WqkvT [3072][1024]
//   [6291456  ) WprojT[1024][1024]
//   [8388608  ) W1T   [4096][1024]
//   [16777216 ) W2T   [1024][4096]
//   [25165824 ) WtT   [6144][1024]
//   [37748736 ) tp    [4][6144] f32
//   [37847040 ) hbuf  [8192][1024] bf16  (LN1 out -> vT[64][64][2048] -> LN2 out)
//   [54624256 ) qkv   [8192][3072] bf16  } overlaid midb [8192][4096]
//   [121733120) attnb [8192][1024] bf16
//   [138510336) x1    [8192][1024] f32   (ends 172064768)
// ---------------------------------------------------------------------------

typedef __attribute__((ext_vector_type(8))) __bf16 bf16x8;
typedef __attribute__((ext_vector_type(4))) float f32x4;

union FragU { uint4 u; bf16x8 b; };

#define AS1(p) ((const __attribute__((address_space(1))) void*)(p))
#define AS3(p) ((__attribute__((address_space(3))) void*)(p))

__device__ __forceinline__ float bflo(uint u) {
    union { uint i; float f; } v; v.i = u << 16; return v.f;
}
__device__ __forceinline__ float bfhi(uint u) {
    union { uint i; float f; } v; v.i = u & 0xffff0000u; return v.f;
}
__device__ __forceinline__ ushort f2bf(float f) {
    union { float f; uint i; } v; v.f = f;
    uint r = (v.i + 0x7fffu + ((v.i >> 16) & 1u)) >> 16;
    return (ushort)r;
}
// truncating bf16 pair pack: low half <- a, high half <- b (1 v_perm_b32)
__device__ __forceinline__ uint pkbf(float a, float b) {
    return __builtin_amdgcn_perm(__float_as_uint(b), __float_as_uint(a), 0x07060302u);
}
__device__ __forceinline__ void stval(ushort* p, float v) { *p = f2bf(v); }
__device__ __forceinline__ void stval(float* p, float v) { *p = v; }

// tanh-form GELU via native exp2; |err| ~1e-3 (threshold slack is 0.08)
__device__ __forceinline__ float gelu_f(float x) {
    float y = 0.7978845608f * (x + 0.044715f * x * x * x);
    float e = exp2f(y * 2.88539008178f);      // exp(2y)
    float t = 1.f - 2.f / (1.f + e);          // tanh(y)
    return 0.5f * x * (1.f + t);
}

// ---------------------------------------------------------------------------
// Transpose + fp32->bf16: in [R][C] f32 -> out [C][R] bf16.
// ---------------------------------------------------------------------------
__global__ __launch_bounds__(256) void transpose_f2b(const float* __restrict__ in,
                                                     ushort* __restrict__ out,
                                                     int R, int C) {
    __shared__ ushort t[32][33];
    int c0 = blockIdx.x * 32, r0 = blockIdx.y * 32;
    int tx = threadIdx.x, ty = threadIdx.y;  // block (32, 8)
#pragma unroll
    for (int i = 0; i < 32; i += 8)
        t[ty + i][tx] = f2bf(in[(size_t)(r0 + ty + i) * C + c0 + tx]);
    __syncthreads();
#pragma unroll
    for (int i = 0; i < 32; i += 8)
        out[(size_t)(c0 + ty + i) * R + r0 + tx] = t[tx][ty + i];
}

// ---------------------------------------------------------------------------
// V transpose: qkv [8192][3072] (V = cols 2048+h*64+d) -> vT[bh=64][d=64][l=2048]
// ---------------------------------------------------------------------------
__global__ __launch_bounds__(256) void transpose_v(const ushort* __restrict__ qkv,
                                                   ushort* __restrict__ vT) {
    int bh = blockIdx.x >> 5, lt = blockIdx.x & 31;
    int b = bh >> 4, h = bh & 15;
    int d = threadIdx.x & 63, lg = threadIdx.x >> 6;
    const ushort* src = qkv + (size_t)b * 2048 * 3072 + 2048 + h * 64 + d;
#pragma unroll
    for (int g = 0; g < 2; g++) {
        int l0 = lt * 64 + lg * 16 + g * 8;
        ushort v[8];
#pragma unroll
        for (int i = 0; i < 8; i++) v[i] = src[(size_t)(l0 + i) * 3072];
        *(uint4*)&vT[((size_t)bh * 64 + d) * 2048 + l0] = *(uint4*)v;
    }
}

// ---------------------------------------------------------------------------
// tp = silu(time_emb) @ Wt + bt.  One wave per output element (b, n).
// ---------------------------------------------------------------------------
__global__ __launch_bounds__(256) void tp_gemm(const float* __restrict__ te,
                                               const ushort* __restrict__ WtT,
                                               const float* __restrict__ bt,
                                               float* __restrict__ tp) {
    int w = blockIdx.x * 4 + (threadIdx.x >> 6);
    int lane = threadIdx.x & 63;
    int b = w / 6144, n = w % 6144;
    const ushort* wr = WtT + (size_t)n * 1024;
    const float* tr = te + (size_t)b * 1024;
    float s = 0.f;
#pragma unroll
    for (int i = 0; i < 16; i++) {
        int k = lane + 64 * i;
        float t = tr[k];
        float sil = t / (1.f + __expf(-t));
        s += sil * bflo((uint)wr[k]);
    }
#pragma unroll
    for (int x = 32; x; x >>= 1) s += __shfl_xor(s, x);
    if (lane == 0) tp[(size_t)b * 6144 + n] = s + bt[n];
}

// ---------------------------------------------------------------------------
// Fused LayerNorm + AdaLN modulate: out = (ln(x)*g+be)*(1+scale)+shift.
// ---------------------------------------------------------------------------
__global__ __launch_bounds__(256) void ln_mod(const float* __restrict__ x,
                                              const float* __restrict__ tpb,
                                              const float* __restrict__ g,
                                              const float* __restrict__ be,
                                              ushort* __restrict__ out,
                                              int shift_off, int scale_off) {
    __shared__ float2 sred[4];
    int row = blockIdx.x;
    int b = row >> 11;
    int tid = threadIdx.x;
    float4 f = *(const float4*)&x[(size_t)row * 1024 + tid * 4];
    float v[4] = {f.x, f.y, f.z, f.w};
    float s = v[0] + v[1] + v[2] + v[3];
    float s2 = v[0] * v[0] + v[1] * v[1] + v[2] * v[2] + v[3] * v[3];
#pragma unroll
    for (int m = 32; m; m >>= 1) { s += __shfl_xor(s, m); s2 += __shfl_xor(s2, m); }
    if ((tid & 63) == 0) sred[tid >> 6] = make_float2(s, s2);
    __syncthreads();
    s = sred[0].x + sred[1].x + sred[2].x + sred[3].x;
    s2 = sred[0].y + sred[1].y + sred[2].y + sred[3].y;
    float mu = s * (1.f / 1024.f);
    float var = s2 * (1.f / 1024.f) - mu * mu;
    float rs = rsqrtf(var + 1e-5f);
    const float* tprow = tpb + (size_t)b * 6144;
    ushort o4[4];
#pragma unroll
    for (int t = 0; t < 4; t++) {
        int c = tid * 4 + t;
        float y = (v[t] - mu) * rs * g[c] + be[c];
        y = y * (1.f + tprow[scale_off + c]) + tprow[shift_off + c];
        o4[t] = f2bf(y);
    }
    *(uint2*)&out[(size_t)row * 1024 + tid * 4] = *(uint2*)o4;
}

// ---------------------------------------------------------------------------
// MFMA bf16 GEMM, BK=64 per barrier-pair: two BK=32 chunks double-staged via
// 8x global_load_lds, then 32 MFMAs between barriers. 128x128 tile.
// EPI 0: +bias   EPI 1: gelu(+bias)   EPI 2: res + gate*( +bias )
// ---------------------------------------------------------------------------
template <int EPI, typename OT>
__global__ __launch_bounds__(256) void gemm_bt(const ushort* __restrict__ A,
                                               const ushort* __restrict__ BT,
                                               const float* __restrict__ bias,
                                               OT* __restrict__ C,
                                               int M, int N, int K,
                                               const float* __restrict__ res,
                                               const float* __restrict__ tpb,
                                               int goff) {
    __shared__ __align__(16) ushort As[2][128 * 32];
    __shared__ __align__(16) ushort Bs[2][128 * 32];
    int m0 = blockIdx.y * 128, n0 = blockIdx.x * 128;
    int tid = threadIdx.x;
    int wid = tid >> 6, lane = tid & 63;
    int wy = wid >> 1, wx = wid & 1;
    int r16 = lane & 15;
    int q8 = (lane >> 4) << 3;

    f32x4 acc[4][4];
#pragma unroll
    for (int i = 0; i < 4; i++)
#pragma unroll
        for (int j = 0; j < 4; j++) acc[i][j] = (f32x4){0.f, 0.f, 0.f, 0.f};

    int sr = tid >> 2;            // 0..63
    int sc = (tid & 3) << 3;      // 0,8,16,24
    const ushort* Abase = A + (size_t)(m0 + sr) * K + sc;
    const ushort* Bbase = BT + (size_t)(n0 + sr) * K + sc;

    for (int k0 = 0; k0 < K; k0 += 64) {
#pragma unroll
        for (int c = 0; c < 2; c++) {
            ushort* AsW = As[c] + wid * 512;
            ushort* BsW = Bs[c] + wid * 512;
            int kk = k0 + 32 * c;
            __builtin_amdgcn_global_load_lds(AS1(Abase + kk), AS3(AsW), 16, 0, 0);
            __builtin_amdgcn_global_load_lds(AS1(Abase + (size_t)64 * K + kk), AS3(AsW + 2048), 16, 0, 0);
            __builtin_amdgcn_global_load_lds(AS1(Bbase + kk), AS3(BsW), 16, 0, 0);
            __builtin_amdgcn_global_load_lds(AS1(Bbase + (size_t)64 * K + kk), AS3(BsW + 2048), 16, 0, 0);
        }
        __syncthreads();
#pragma unroll
        for (int c = 0; c < 2; c++) {
            FragU fa[4], fb[4];
#pragma unroll
            for (int i = 0; i < 4; i++)
                fa[i].u = *(const uint4*)&As[c][(wy * 64 + i * 16 + r16) * 32 + q8];
#pragma unroll
            for (int j = 0; j < 4; j++)
                fb[j].u = *(const uint4*)&Bs[c][(wx * 64 + j * 16 + r16) * 32 + q8];
#pragma unroll
            for (int i = 0; i < 4; i++)
#pragma unroll
                for (int j = 0; j < 4; j++)
                    acc[i][j] = __builtin_amdgcn_mfma_f32_16x16x32_bf16(fa[i].b, fb[j].b, acc[i][j], 0, 0, 0);
        }
        __syncthreads();
    }

    int q4 = (lane >> 4) << 2;
#pragma unroll
    for (int i = 0; i < 4; i++) {
#pragma unroll
        for (int j = 0; j < 4; j++) {
            int col = n0 + wx * 64 + j * 16 + r16;
            float bv = bias[col];
#pragma unroll
            for (int t = 0; t < 4; t++) {
                int row = m0 + wy * 64 + i * 16 + q4 + t;
                float v = acc[i][j][t] + bv;
                if constexpr (EPI == 1) {
                    v = gelu_f(v);
                }
                if constexpr (EPI == 2) {
                    float rv = res[(size_t)row * N + col];
                    float gate = tpb[(size_t)(row >> 11) * 6144 + goff + col];
                    v = rv + gate * v;
                }
                stval(&C[(size_t)row * N + col], v);
            }
        }
    }
}

// ---------------------------------------------------------------------------
// MFMA flash attention, transposed-S formulation. V from pre-transposed
// vT[bh][d][l]. exp2-native softmax. LDS: Ks+Vs+Ps = 27 KB.
// ---------------------------------------------------------------------------
__global__ __launch_bounds__(256, 4) void attn_mfma(const ushort* __restrict__ qkv,
                                                    const ushort* __restrict__ vT,
                                                    ushort* __restrict__ out) {
    __shared__ __align__(16) ushort Ks[64 * 72];
    __shared__ __align__(16) ushort Vs[64 * 72];
    __shared__ __align__(16) ushort Ps[64 * 72];   // Q staging in phase 0

    int tid = threadIdx.x;
    int wid = tid >> 6, lane = tid & 63;
    int r16 = lane & 15, quad = lane >> 4;
    int q8 = quad << 3, q4 = quad << 2;

    int bh = blockIdx.x >> 5;        // 0..63
    int qt = blockIdx.x & 31;        // 0..31
    int b = bh >> 4, h = bh & 15;
    const ushort* qkbase = qkv + (size_t)b * 2048 * 3072 + h * 64;
    const float SC = 0.18033688011f; // 0.125 * log2(e)

    // ---- phase 0: stage Q tile [64][64] into Ps, load wave's Q frags ----
    {
        int r = tid >> 2;                 // 0..63
        int c = (tid & 3) << 4;           // 0,16,32,48
        const ushort* qp = qkbase + (size_t)(qt * 64 + r) * 3072 + c;
        *(uint4*)&Ps[r * 72 + c] = *(const uint4*)qp;
        *(uint4*)&Ps[r * 72 + c + 8] = *(const uint4*)(qp + 8);
    }
    __syncthreads();
    FragU qa[2];
#pragma unroll
    for (int ks = 0; ks < 2; ks++)
        qa[ks].u = *(const uint4*)&Ps[(wid * 16 + r16) * 72 + ks * 32 + q8];
    // From here each wave only touches its own 16 Ps rows (wave-private).

    float m_ = -1e30f, l_ = 0.f;          // scalars: this lane's q-row = r16
    f32x4 o[4];
#pragma unroll
    for (int dn = 0; dn < 4; dn++) o[dn] = (f32x4){0.f, 0.f, 0.f, 0.f};

    int kr = tid >> 2;                    // 0..63
    int kc = (tid & 3) << 4;              // 0,16,32,48
    const ushort* kptr = qkbase + 1024 + (size_t)kr * 3072 + kc;
    const ushort* vptr = vT + (size_t)bh * 131072 + (size_t)kr * 2048 + kc;

    // prefetch tile 0
    uint4 ka0 = *(const uint4*)kptr;
    uint4 ka1 = *(const uint4*)(kptr + 8);
    uint4 va0 = *(const uint4*)vptr;
    uint4 va1 = *(const uint4*)(vptr + 8);

    for (int kt = 0; kt < 32; kt++) {
        __syncthreads();   // previous tile's LDS readers done
        *(uint4*)&Ks[kr * 72 + kc] = ka0;
        *(uint4*)&Ks[kr * 72 + kc + 8] = ka1;
        *(uint4*)&Vs[kr * 72 + kc] = va0;
        *(uint4*)&Vs[kr * 72 + kc + 8] = va1;
        __syncthreads();

        // prefetch next tile; loads complete during compute below
        if (kt < 31) {
            const ushort* kp2 = kptr + (size_t)(kt + 1) * 64 * 3072;
            const ushort* vp2 = vptr + (kt + 1) * 64;
            ka0 = *(const uint4*)kp2;
            ka1 = *(const uint4*)(kp2 + 8);
            va0 = *(const uint4*)vp2;
            va1 = *(const uint4*)(vp2 + 8);
        }

        // ---- S^T = K Q^T  (lane holds keys n*16+q4+t for q-row r16) ----
        f32x4 s[4];
#pragma unroll
        for (int n = 0; n < 4; n++) s[n] = (f32x4){0.f, 0.f, 0.f, 0.f};
#pragma unroll
        for (int ks = 0; ks < 2; ks++) {
            FragU kb[4];
#pragma unroll
            for (int n = 0; n < 4; n++)
                kb[n].u = *(const uint4*)&Ks[(n * 16 + r16) * 72 + ks * 32 + q8];
#pragma unroll
            for (int n = 0; n < 4; n++)
                s[n] = __builtin_amdgcn_mfma_f32_16x16x32_bf16(kb[n].b, qa[ks].b, s[n], 0, 0, 0);
        }

        // ---- online softmax (exp2-native): scalar per lane ----
        float mx = fmaxf(fmaxf(fmaxf(s[0][0], s[0][1]), fmaxf(s[0][2], s[0][3])),
                         fmaxf(fmaxf(s[1][0], s[1][1]), fmaxf(s[1][2], s[1][3])));
        mx = fmaxf(mx, fmaxf(fmaxf(fmaxf(s[2][0], s[2][1]), fmaxf(s[2][2], s[2][3])),
                             fmaxf(fmaxf(s[3][0], s[3][1]), fmaxf(s[3][2], s[3][3]))));
        mx = fmaxf(mx, __shfl_xor(mx, 16));
        mx = fmaxf(mx, __shfl_xor(mx, 32));
        float nm = fmaxf(m_, mx);
        float al = exp2f((m_ - nm) * SC);
        float cc = nm * SC;
        m_ = nm;

        float p[4][4];
        float ps = 0.f;
#pragma unroll
        for (int n = 0; n < 4; n++)
#pragma unroll
            for (int t = 0; t < 4; t++) {
                p[n][t] = exp2f(__fmaf_rn(s[n][t], SC, -cc));
                ps += p[n][t];
            }
        ps += __shfl_xor(ps, 16);
        ps += __shfl_xor(ps, 32);
        l_ = l_ * al + ps;
#pragma unroll
        for (int dn = 0; dn < 4; dn++)
#pragma unroll
            for (int t = 0; t < 4; t++) o[dn][t] *= al;

        // ---- P -> Ps[qrow=r16][key] (wave-private rows, 4x b64 writes) ----
#pragma unroll
        for (int n = 0; n < 4; n++) {
            uint2 w2 = make_uint2(pkbf(p[n][0], p[n][1]), pkbf(p[n][2], p[n][3]));
            *(uint2*)&Ps[(wid * 16 + r16) * 72 + n * 16 + q4] = w2;
        }

        // ---- O^T += V^T P^T ----
#pragma unroll
        for (int ks = 0; ks < 2; ks++) {
            FragU pa, vb[4];
            pa.u = *(const uint4*)&Ps[(wid * 16 + r16) * 72 + ks * 32 + q8];
#pragma unroll
            for (int dn = 0; dn < 4; dn++)
                vb[dn].u = *(const uint4*)&Vs[(dn * 16 + r16) * 72 + ks * 32 + q8];
#pragma unroll
            for (int dn = 0; dn < 4; dn++)
                o[dn] = __builtin_amdgcn_mfma_f32_16x16x32_bf16(vb[dn].b, pa.b, o[dn], 0, 0, 0);
        }
    }

    // ---- epilogue: lane holds O^T[d=dn*16+q4+t][qrow=r16] ----
    float inv = 1.f / l_;
    int row = qt * 64 + wid * 16 + r16;
    ushort* orow = out + (size_t)(b * 2048 + row) * 1024 + h * 64;
#pragma unroll
    for (int dn = 0; dn < 4; dn++) {
        uint2 w2 = make_uint2(pkbf(o[dn][0] * inv, o[dn][1] * inv),
                              pkbf(o[dn][2] * inv, o[dn][3] * inv));
        *(uint2*)&orow[dn * 16 + q4] = w2;
    }
}

// ---------------------------------------------------------------------------
extern "C" void kernel_launch(void* const* d_in, const int* in_sizes, int n_in,
                              void* d_out, int out_size, void* d_ws, size_t ws_size,
                              hipStream_t stream) {
    const float* x    = (const float*)d_in[0];
    const float* te   = (const float*)d_in[1];
    const float* Wqkv = (const float*)d_in[2];
    const float* bqkv = (const float*)d_in[3];
    const float* Wproj= (const float*)d_in[4];
    const float* bproj= (const float*)d_in[5];
    const float* W1   = (const float*)d_in[6];
    const float* b1   = (const float*)d_in[7];
    const float* W2   = (const float*)d_in[8];
    const float* b2   = (const float*)d_in[9];
    const float* Wt   = (const float*)d_in[10];
    const float* bt   = (const float*)d_in[11];
    const float* g1   = (const float*)d_in[12];
    const float* be1  = (const float*)d_in[13];
    const float* g2   = (const float*)d_in[14];
    const float* be2  = (const float*)d_in[15];

    char* ws = (char*)d_ws;
    ushort* WqkvT  = (ushort*)(ws + 0);
    ushort* WprojT = (ushort*)(ws + 6291456);
    ushort* W1T    = (ushort*)(ws + 8388608);
    ushort* W2T    = (ushort*)(ws + 16777216);
    ushort* WtT    = (ushort*)(ws + 25165824);
    float*  tpb    = (float*)(ws + 37748736);
    ushort* hbuf   = (ushort*)(ws + 37847040);
    ushort* vTb    = (ushort*)(ws + 37847040);   // overlays hbuf (dead there)
    ushort* qkvb   = (ushort*)(ws + 54624256);
    ushort* midb   = (ushort*)(ws + 54624256);   // overlays qkv (dead by then)
    ushort* attnb  = (ushort*)(ws + 121733120);
    float*  x1b    = (float*)(ws + 138510336);

    dim3 tb(32, 8);
    hipLaunchKernelGGL(transpose_f2b, dim3(3072 / 32, 1024 / 32), tb, 0, stream, Wqkv, WqkvT, 1024, 3072);
    hipLaunchKernelGGL(transpose_f2b, dim3(1024 / 32, 1024 / 32), tb, 0, stream, Wproj, WprojT, 1024, 1024);
    hipLaunchKernelGGL(transpose_f2b, dim3(4096 / 32, 1024 / 32), tb, 0, stream, W1, W1T, 1024, 4096);
    hipLaunchKernelGGL(transpose_f2b, dim3(1024 / 32, 4096 / 32), tb, 0, stream, W2, W2T, 4096, 1024);
    hipLaunchKernelGGL(transpose_f2b, dim3(6144 / 32, 1024 / 32), tb, 0, stream, Wt, WtT, 1024, 6144);

    hipLaunchKernelGGL(tp_gemm, dim3(6144), dim3(256), 0, stream, te, WtT, bt, tpb);

    // LN1 + modulate (shift_msa @0, scale_msa @1024)
    hipLaunchKernelGGL(ln_mod, dim3(8192), dim3(256), 0, stream, x, tpb, g1, be1, hbuf, 0, 1024);

    // qkv = h @ Wqkv + bqkv
    hipLaunchKernelGGL((gemm_bt<0, ushort>), dim3(3072 / 128, 8192 / 128), dim3(256), 0, stream,
                       hbuf, WqkvT, bqkv, qkvb, 8192, 3072, 1024, (const float*)nullptr, (const float*)nullptr, 0);

    // V -> vT[bh][d][l]  (hbuf region is dead after the qkv GEMM consumed it)
    hipLaunchKernelGGL(transpose_v, dim3(2048), dim3(256), 0, stream, qkvb, vTb);

    hipLaunchKernelGGL(attn_mfma, dim3(2048), dim3(256), 0, stream, qkvb, vTb, attnb);

    // x1 = x + gate_msa * (attn @ Wproj + bproj)   (gate_msa @2048)
    hipLaunchKernelGGL((gemm_bt<2, float>), dim3(1024 / 128, 8192 / 128), dim3(256), 0, stream,
                       attnb, WprojT, bproj, x1b, 8192, 1024, 1024, x, tpb, 2048);

    // LN2 + modulate (shift_mlp @3072, scale_mlp @4096)
    hipLaunchKernelGGL(ln_mod, dim3(8192), dim3(256), 0, stream, x1b, tpb, g2, be2, hbuf, 3072, 4096);

    // mid = gelu(h @ W1 + b1)
    hipLaunchKernelGGL((gemm_bt<1, ushort>), dim3(4096 / 128, 8192 / 128), dim3(256), 0, stream,
                       hbuf, W1T, b1, midb, 8192, 4096, 1024, (const float*)nullptr, (const float*)nullptr, 0);

    // out = x1 + gate_mlp * (mid @ W2 + b2)   (gate_mlp @5120)
    hipLaunchKernelGGL((gemm_bt<2, float>), dim3(1024 / 128, 8192 / 128), dim3(256), 0, stream,
                       midb, W2T, b2, (float*)d_out, 8192, 1024, 4096, x1b, tpb, 5120);
}